// Round 6
// baseline (76.407 us; speedup 1.0000x reference)
//
#include <hip/hip_runtime.h>
#include <hip/hip_bf16.h>
#include <stdint.h>

typedef __bf16 bf16x8 __attribute__((ext_vector_type(8)));
typedef float f32x4 __attribute__((ext_vector_type(4)));
typedef unsigned short ushort8 __attribute__((ext_vector_type(8)));

#define NQ 8192
#define NP 4096
#define DD 512
#define NTILES 8  // DD / 64

__device__ inline unsigned short f32_to_bf16_rne(float f) {
  union { float f; uint32_t u; } v; v.f = f;
  uint32_t u = v.u;
  return (unsigned short)((u + 0x7fffu + ((u >> 16) & 1u)) >> 16);
}

// One wave per row: fp32 -> bf16 copy + fp32 sum-of-squares per row.
__global__ __launch_bounds__(256) void cvt_norms_kernel(
    const float* __restrict__ X, const float* __restrict__ Y,
    unsigned short* __restrict__ Xb, unsigned short* __restrict__ Yb,
    float* __restrict__ xsq, float* __restrict__ ysq) {
  const int wave = threadIdx.x >> 6;
  const int lane = threadIdx.x & 63;
  const int row = blockIdx.x * 4 + wave;  // 0..12287

  const float* src;
  unsigned short* dst;
  float* nrm;
  if (row < NQ) {
    src = X + (size_t)row * DD;
    dst = Xb + (size_t)row * DD;
    nrm = xsq + row;
  } else {
    const int r = row - NQ;
    src = Y + (size_t)r * DD;
    dst = Yb + (size_t)r * DD;
    nrm = ysq + r;
  }

  const float4 v0 = *(const float4*)(src + lane * 8);
  const float4 v1 = *(const float4*)(src + lane * 8 + 4);
  float s = v0.x * v0.x + v0.y * v0.y + v0.z * v0.z + v0.w * v0.w +
            v1.x * v1.x + v1.y * v1.y + v1.z * v1.z + v1.w * v1.w;

  ushort8 o;
  o[0] = f32_to_bf16_rne(v0.x);
  o[1] = f32_to_bf16_rne(v0.y);
  o[2] = f32_to_bf16_rne(v0.z);
  o[3] = f32_to_bf16_rne(v0.w);
  o[4] = f32_to_bf16_rne(v1.x);
  o[5] = f32_to_bf16_rne(v1.y);
  o[6] = f32_to_bf16_rne(v1.z);
  o[7] = f32_to_bf16_rne(v1.w);
  *(ushort8*)(dst + lane * 8) = o;

  #pragma unroll
  for (int off = 32; off; off >>= 1) s += __shfl_xor(s, off, 64);
  if (lane == 0) *nrm = s;
}

// ---------------------------------------------------------------------------
// 128x128-tile NT GEMM (C = Xb * Yb^T), BK=64, 4 waves (2x2, wave 64x64),
// r2's exact 4-phase schedule/waits, 64 KiB LDS => TWO blocks per CU:
// block A's LDS-read/stage window overlaps block B's MFMA window via the CU
// scheduler (m114 wave-level overlap) -- the single-block r2 config serialized
// those windows behind block-wide barriers.
//
// LDS (64 KiB): A [buf][ks][128r][32c]: REG_A = buf*16384 + ks*8192.
//               B same at +32768.
// Swizzle: 16B-chunk XOR keyed by (row>>1)&3, both sides.
//
// Per-wave ledger (every stage = 2 loads/wave; prologue 7 stages = 14):
//   in-loop stage order: Ph1->B1(g+1), Ph2->A0(g+2), Ph3->B0(g+2), Ph4->A1(g+2)
//   load numbering: A0(g)=#8g+1..2, B0(g)=#8g+3..4, A1(g)=#8g+5..6, B1(g)=#8g+7..8
//   vmcnt(10) at Ph4(g-1) (issued 8g+14) certifies #<=8g+4 = A0,B0(g) before
//     Ph1(g)'s reads; vmcnt(10) at Ph2(g) (issued 8g+18) certifies #<=8g+8 =
//     A1,B1(g) before Ph3(g)'s reads; prologue vmcnt(10) certifies A0,B0(0).
//   WAR: each region's readers drain (per-wave lgkm(0) + end barrier) before
//   the overwriting stage issues (one tile later).
// ---------------------------------------------------------------------------
__global__ __launch_bounds__(256, 2) void dist_gemm_kernel(
    const unsigned short* __restrict__ Xb, const unsigned short* __restrict__ Yb,
    const float* __restrict__ xsq, const float* __restrict__ ysq,
    float* __restrict__ out) {
  __shared__ __align__(128) unsigned char lds[65536];

  const int tid = threadIdx.x;
  const int wave = tid >> 6;
  const int lane = tid & 63;
  const int fr = lane & 15, fq = lane >> 4;
  const int wr = wave >> 1;  // 0..1: rows wr*64..+64
  const int wc = wave & 1;   // 0..1: cols wc*64..+64

  // XCD swizzle: 2048 blocks, 256 contiguous wgids per XCD (bijective).
  const int bid = blockIdx.x;
  const int wgid = (bid & 7) * 256 + (bid >> 3);
  const int tileN = wgid & 31;   // 32 N-tiles (128 cols each)
  const int tileM = wgid >> 5;   // 64 M-tiles (128 rows each)
  const int brow = tileM * 128;
  const int bcol = tileN * 128;

#define REG_A(buf, ks) ((unsigned)((buf)*16384 + (ks)*8192))
#define REG_B(buf, ks) ((unsigned)(32768 + (buf)*16384 + (ks)*8192))

  // stage one 8KB half-tile (khalf ks of K-tile t); 2 loads/thread.
  auto stage = [&](int buf, int t, int ks, bool isA) {
    const unsigned short* base =
        isA ? (Xb + (size_t)brow * DD) : (Yb + (size_t)bcol * DD);
    const unsigned ldsbase = (isA ? REG_A(buf, ks) : REG_B(buf, ks));
    const int tt = t & 7;
    #pragma unroll
    for (int i = 0; i < 2; ++i) {
      const unsigned P0 = (unsigned)(wave * 2 + i) * 1024u;  // wave-uniform
      const unsigned P = P0 + (unsigned)lane * 16u;          // lane's dst byte
      const unsigned L = P ^ (((P >> 7) & 3u) << 4);         // inverse swizzle
      const unsigned row = L >> 6;
      const unsigned col = (L & 63u) >> 1;
      const unsigned short* src =
          base + (size_t)row * DD + tt * 64 + ks * 32 + col;
      __builtin_amdgcn_global_load_lds(
          (const __attribute__((address_space(1))) void*)src,
          (__attribute__((address_space(3))) void*)(lds + ldsbase + P0),
          16, 0, 0);
    }
  };

  // fragment read offsets (swizzled)
  const unsigned cswz = (unsigned)((fq ^ ((fr >> 1) & 3)) << 4);
  const unsigned rA = (unsigned)((wr * 64 + fr) * 64) + cswz;  // + m*1024
  const unsigned rB = (unsigned)((wc * 64 + fr) * 64) + cswz;  // + n*1024

  f32x4 acc[4][4] = {};
  bf16x8 a[4], b0, b1, b2, b3;

  // ---- prologue: A0(0) B0(0) A1(0) B1(0) A0(1) B0(1) A1(1) = 14 loads ----
  stage(0, 0, 0, true);
  stage(0, 0, 0, false);
  stage(0, 0, 1, true);
  stage(0, 0, 1, false);
  stage(1, 1, 0, true);
  stage(1, 1, 0, false);
  stage(1, 1, 1, true);
  asm volatile("s_waitcnt vmcnt(10)" ::: "memory");
  __builtin_amdgcn_s_barrier();

  #pragma unroll 2
  for (int g = 0; g < NTILES; ++g) {
    const int buf = g & 1;

    // ---- Ph1: ks=0, n 0..1 ----
    #pragma unroll
    for (int m = 0; m < 4; ++m)
      a[m] = *(const bf16x8*)(lds + REG_A(buf, 0) + rA + (unsigned)m * 1024u);
    b0 = *(const bf16x8*)(lds + REG_B(buf, 0) + rB + 0u);
    b1 = *(const bf16x8*)(lds + REG_B(buf, 0) + rB + 1024u);
    stage(buf ^ 1, g + 1, 1, false);  // B1(g+1)
    __builtin_amdgcn_s_barrier();
    asm volatile("s_waitcnt lgkmcnt(0)" ::: "memory");
    __builtin_amdgcn_sched_barrier(0);
    __builtin_amdgcn_s_setprio(1);
    #pragma unroll
    for (int m = 0; m < 4; ++m) {
      acc[m][0] = __builtin_amdgcn_mfma_f32_16x16x32_bf16(a[m], b0, acc[m][0], 0, 0, 0);
      acc[m][1] = __builtin_amdgcn_mfma_f32_16x16x32_bf16(a[m], b1, acc[m][1], 0, 0, 0);
    }
    __builtin_amdgcn_s_setprio(0);
    __builtin_amdgcn_s_barrier();

    // ---- Ph2: ks=0, n 2..3 ----
    b2 = *(const bf16x8*)(lds + REG_B(buf, 0) + rB + 2048u);
    b3 = *(const bf16x8*)(lds + REG_B(buf, 0) + rB + 3072u);
    stage(buf, g + 2, 0, true);  // A0(g+2)
    asm volatile("s_waitcnt vmcnt(10)" ::: "memory");
    __builtin_amdgcn_s_barrier();
    asm volatile("s_waitcnt lgkmcnt(0)" ::: "memory");
    __builtin_amdgcn_sched_barrier(0);
    __builtin_amdgcn_s_setprio(1);
    #pragma unroll
    for (int m = 0; m < 4; ++m) {
      acc[m][2] = __builtin_amdgcn_mfma_f32_16x16x32_bf16(a[m], b2, acc[m][2], 0, 0, 0);
      acc[m][3] = __builtin_amdgcn_mfma_f32_16x16x32_bf16(a[m], b3, acc[m][3], 0, 0, 0);
    }
    __builtin_amdgcn_s_setprio(0);
    __builtin_amdgcn_s_barrier();

    // ---- Ph3: ks=1, n 0..1 ----
    #pragma unroll
    for (int m = 0; m < 4; ++m)
      a[m] = *(const bf16x8*)(lds + REG_A(buf, 1) + rA + (unsigned)m * 1024u);
    b0 = *(const bf16x8*)(lds + REG_B(buf, 1) + rB + 0u);
    b1 = *(const bf16x8*)(lds + REG_B(buf, 1) + rB + 1024u);
    stage(buf, g + 2, 0, false);  // B0(g+2)
    __builtin_amdgcn_s_barrier();
    asm volatile("s_waitcnt lgkmcnt(0)" ::: "memory");
    __builtin_amdgcn_sched_barrier(0);
    __builtin_amdgcn_s_setprio(1);
    #pragma unroll
    for (int m = 0; m < 4; ++m) {
      acc[m][0] = __builtin_amdgcn_mfma_f32_16x16x32_bf16(a[m], b0, acc[m][0], 0, 0, 0);
      acc[m][1] = __builtin_amdgcn_mfma_f32_16x16x32_bf16(a[m], b1, acc[m][1], 0, 0, 0);
    }
    __builtin_amdgcn_s_setprio(0);
    __builtin_amdgcn_s_barrier();

    // ---- Ph4: ks=1, n 2..3 ----
    b2 = *(const bf16x8*)(lds + REG_B(buf, 1) + rB + 2048u);
    b3 = *(const bf16x8*)(lds + REG_B(buf, 1) + rB + 3072u);
    stage(buf, g + 2, 1, true);  // A1(g+2)
    asm volatile("s_waitcnt vmcnt(10)" ::: "memory");
    __builtin_amdgcn_s_barrier();
    asm volatile("s_waitcnt lgkmcnt(0)" ::: "memory");
    __builtin_amdgcn_sched_barrier(0);
    __builtin_amdgcn_s_setprio(1);
    #pragma unroll
    for (int m = 0; m < 4; ++m) {
      acc[m][2] = __builtin_amdgcn_mfma_f32_16x16x32_bf16(a[m], b2, acc[m][2], 0, 0, 0);
      acc[m][3] = __builtin_amdgcn_mfma_f32_16x16x32_bf16(a[m], b3, acc[m][3], 0, 0, 0);
    }
    __builtin_amdgcn_s_setprio(0);
    __builtin_amdgcn_s_barrier();
  }

  // ---- epilogue: out[row][col] = (xsq[row] + ysq[col] - 2*acc) / 512 ----
  float ysv[4];
  #pragma unroll
  for (int n = 0; n < 4; ++n) ysv[n] = ysq[bcol + wc * 64 + n * 16 + fr];

  #pragma unroll
  for (int m = 0; m < 4; ++m) {
    const int rowb = brow + wr * 64 + m * 16 + fq * 4;
    float xsv[4];
    #pragma unroll
    for (int r = 0; r < 4; ++r) xsv[r] = xsq[rowb + r];
    #pragma unroll
    for (int n = 0; n < 4; ++n) {
      const int col = bcol + wc * 64 + n * 16 + fr;
      #pragma unroll
      for (int r = 0; r < 4; ++r) {
        out[(size_t)(rowb + r) * NP + col] =
            (xsv[r] + ysv[n] - 2.0f * acc[m][n][r]) * (1.0f / 512.0f);
      }
    }
  }
}

extern "C" void kernel_launch(void* const* d_in, const int* in_sizes, int n_in,
                              void* d_out, int out_size, void* d_ws, size_t ws_size,
                              hipStream_t stream) {
  const float* X = (const float*)d_in[0];  // z_queries (8192, 512)
  const float* Y = (const float*)d_in[1];  // class_prototypes (4096, 512)
  float* out = (float*)d_out;              // (8192, 4096)

  unsigned short* Xb = (unsigned short*)d_ws;   // 8192*512 bf16
  unsigned short* Yb = Xb + (size_t)NQ * DD;    // 4096*512 bf16
  float* xsq = (float*)(Yb + (size_t)NP * DD);  // 8192 f32
  float* ysq = xsq + NQ;                        // 4096 f32

  cvt_norms_kernel<<<(NQ + NP) / 4, 256, 0, stream>>>(X, Y, Xb, Yb, xsq, ysq);
  dist_gemm_kernel<<<(NQ / 128) * (NP / 128), 256, 0, stream>>>(Xb, Yb, xsq,
                                                                ysq, out);
}